// Round 4
// baseline (350.897 us; speedup 1.0000x reference)
//
#include <hip/hip_runtime.h>
#include <cmath>

// KPConv round 4: R3 structure (both einsums on bf16 MFMA, hi/lo 3-term), plus
// s_feats pre-packed ONCE into ws as uint[N][128] = bf16hi | bf16lo<<16.
// Phase-A gathers load the same dword/element but skip all conversion VALU.
// Fallback (ws too small): R3-proven inline conversion path (template).

constexpr int HN = 32;
constexpr int KP = 15;
constexpr int CI = 128;
constexpr int CO = 128;
constexpr int MB = 32;    // points per block
constexpr int NT = 1024;  // 16 waves
constexpr float INV_SIGMA = 0.5f;
constexpr size_t WOFF = 1048576;   // packed feats start 1 MB into ws (W-pack first)

using short8  = __attribute__((ext_vector_type(8))) short;
using f32x4   = __attribute__((ext_vector_type(4))) float;
using uint4v  = __attribute__((ext_vector_type(4))) unsigned int;

static __device__ __forceinline__ unsigned short f2bf(float x) {
    unsigned u = __float_as_uint(x);
    u += 0x7fff + ((u >> 16) & 1);          // RNE
    return (unsigned short)(u >> 16);
}
static __device__ __forceinline__ float bf2f(unsigned short h) {
    return __uint_as_float(((unsigned)h) << 16);
}
static __device__ __forceinline__ unsigned packhl(float v) {
    unsigned short hi = f2bf(v);
    unsigned short lo = f2bf(v - bf2f(hi));
    return (unsigned)hi | ((unsigned)lo << 16);
}

// ---- prep: W[15][128][128] f32 -> bf16 hi/lo MFMA-B fragments (R2/R3-verified) ----
// fb = (k*4 + s)*8 + dt; ushort layout fb*1024 + plane*512 + lane*8 + j.
// lane l elem j = W[k][c = s*32 + (l>>4)*8 + j][d = dt*16 + (l&15)]
__global__ void kpconv_prep_w(const float* __restrict__ w,
                              unsigned short* __restrict__ ws16) {
    int t = blockIdx.x * blockDim.x + threadIdx.x;
    int fb = t >> 6, lane = t & 63;
    if (fb >= 480) return;
    int k = fb >> 5, s = (fb >> 3) & 3, dt = fb & 7;
    int g = lane >> 4, n = lane & 15;
    unsigned short* base = ws16 + fb * 1024 + lane * 8;
    #pragma unroll
    for (int j = 0; j < 8; ++j) {
        int c = s * 32 + g * 8 + j;
        int d = dt * 16 + n;
        float v = w[(k * CI + c) * CO + d];
        unsigned short hi = f2bf(v);
        unsigned short lo = f2bf(v - bf2f(hi));
        base[j]       = (short)hi;
        base[512 + j] = (short)lo;
    }
}

// ---- prep: s_feats[N][128] f32 -> uint[N][128] (hi | lo<<16) ----
__global__ void kpconv_prep_f(const float* __restrict__ f,
                              unsigned* __restrict__ dst, int total4) {
    int t = blockIdx.x * blockDim.x + threadIdx.x;
    if (t >= total4) return;
    float4 v = ((const float4*)f)[t];
    uint4 o;
    o.x = packhl(v.x); o.y = packhl(v.y); o.z = packhl(v.z); o.w = packhl(v.w);
    ((uint4*)dst)[t] = o;
}

#define MFMA(a, b, c) c = __builtin_amdgcn_mfma_f32_16x16x32_bf16(a, b, c, 0, 0, 0)

template<bool PACKED>
__global__ __launch_bounds__(NT)
void kpconv_main(const float* __restrict__ q_pts,
                 const float* __restrict__ s_pts,
                 const float* __restrict__ s_feats,
                 const int*   __restrict__ nb,
                 const float* __restrict__ kpts,
                 const unsigned short* __restrict__ wfr,
                 const unsigned* __restrict__ fpak,
                 float* __restrict__ out, int M)
{
    __shared__ __align__(16) char pool[65536];

    const int t    = threadIdx.x;
    const int lane = t & 63;
    const int wid  = t >> 6;        // 0..15
    const int g    = lane >> 4;     // 0..3
    const int kk   = lane & 15;
    const int m0   = blockIdx.x * MB;

    const float kx = kpts[kk * 3 + 0];
    const float ky = kpts[kk * 3 + 1];
    const float kz = kpts[kk * 3 + 2];

    f32x4 accA[2][8] = {};   // wf: lane holds rows k=4g+r, col c=ct*16+kk

    // ================= Phase A =================
    #pragma unroll
    for (int pi = 0; pi < 2; ++pi) {
        const int  gp    = m0 + wid * 2 + pi;
        const bool valid = (gp < M);
        const int  rr    = valid ? gp : 0;
        const float qx = q_pts[rr * 3 + 0];
        const float qy = q_pts[rr * 3 + 1];
        const float qz = q_pts[rr * 3 + 2];

        int4 ia = *(const int4*)(nb + rr * HN + g * 8);
        int4 ib = *(const int4*)(nb + rr * HN + g * 8 + 4);
        int idx[8] = { ia.x, ia.y, ia.z, ia.w, ib.x, ib.y, ib.z, ib.w };

        // influence A-fragments (hi/lo), computed in fragment layout
        short8 Ih, Il;
        #pragma unroll
        for (int j = 0; j < 8; ++j) {
            const float* sp = s_pts + idx[j] * 3;
            float rx = sp[0] - qx, ry = sp[1] - qy, rz = sp[2] - qz;
            float dx = rx - kx, dy = ry - ky, dz = rz - kz;
            float d2 = dx * dx + dy * dy + dz * dz;
            float v  = fmaxf(1.0f - sqrtf(d2) * INV_SIGMA, 0.0f);
            if (kk == 15 || !valid) v = 0.0f;
            unsigned short hi = f2bf(v);
            Ih[j] = (short)hi;
            Il[j] = (short)f2bf(v - bf2f(hi));
        }

        if (PACKED) {
            const unsigned* bp[8];
            #pragma unroll
            for (int j = 0; j < 8; ++j) bp[j] = fpak + idx[j] * CI + kk;
            #pragma unroll
            for (int ct = 0; ct < 8; ++ct) {
                unsigned u[8];
                #pragma unroll
                for (int j = 0; j < 8; ++j) u[j] = bp[j][ct * 16];
                uint4v hv, lv;
                #pragma unroll
                for (int d = 0; d < 4; ++d) {
                    unsigned a = u[2 * d], b = u[2 * d + 1];
                    hv[d] = (a & 0xffffu) | (b << 16);
                    lv[d] = (a >> 16)    | (b & 0xffff0000u);
                }
                short8 Fh = __builtin_bit_cast(short8, hv);
                short8 Fl = __builtin_bit_cast(short8, lv);
                MFMA(Ih, Fh, accA[pi][ct]);
                MFMA(Ih, Fl, accA[pi][ct]);
                MFMA(Il, Fh, accA[pi][ct]);
            }
        } else {
            #pragma unroll
            for (int ct = 0; ct < 8; ++ct) {
                float f[8];
                #pragma unroll
                for (int j = 0; j < 8; ++j)
                    f[j] = s_feats[idx[j] * CI + ct * 16 + kk];
                short8 Fh, Fl;
                #pragma unroll
                for (int j = 0; j < 8; ++j) {
                    unsigned short hi = f2bf(f[j]);
                    Fh[j] = (short)hi;
                    Fl[j] = (short)f2bf(f[j] - bf2f(hi));
                }
                MFMA(Ih, Fh, accA[pi][ct]);
                MFMA(Ih, Fl, accA[pi][ct]);
                MFMA(Il, Fh, accA[pi][ct]);
            }
        }
    }

    // ================= Phase B (R3-verified slab GEMM) =================
    const int kq = wid >> 2;    // k-quarter (slab id)
    const int dh = wid & 3;     // d-tiles {2dh, 2dh+1}
    f32x4 accB[2][2] = {};

    #pragma unroll
    for (int tr = 0; tr < 4; ++tr) {
        if (tr) __syncthreads();        // previous round's slab reads done
        // --- write slabs: k = 4g + tr (slab g), value = acc component tr ---
        #pragma unroll
        for (int pi = 0; pi < 2; ++pi) {
            const int prow = wid * 2 + pi;
            char* rowbase = pool + g * 16384 + prow * 256;
            const int rowx = (prow & 7) << 4;
            #pragma unroll
            for (int ct = 0; ct < 8; ++ct) {
                float v = accA[pi][ct][tr];
                unsigned short hi = f2bf(v);
                unsigned short lo = f2bf(v - bf2f(hi));
                int c2  = (ct * 16 + kk) * 2;
                int off = (c2 ^ (g << 5)) ^ rowx;
                *(unsigned short*)(rowbase + off)        = hi;
                *(unsigned short*)(rowbase + 8192 + off) = lo;
            }
        }
        __syncthreads();                // slabs ready
        // --- MFMA: k = 4*kq + tr against pre-packed W fragments ---
        const int k = 4 * kq + tr;
        if (k < KP) {
            #pragma unroll
            for (int sc = 0; sc < 4; ++sc) {
                short8 ah[2], al[2];
                #pragma unroll
                for (int mt = 0; mt < 2; ++mt) {
                    int row = mt * 16 + kk;
                    int c2  = sc * 64 + g * 16;
                    int off = (c2 ^ (kq << 5)) ^ ((row & 7) << 4);
                    const char* base = pool + kq * 16384 + row * 256 + off;
                    ah[mt] = *(const short8*)(base);
                    al[mt] = *(const short8*)(base + 8192);
                }
                const unsigned short* fb0 =
                    wfr + ((k * 4 + sc) * 8 + dh * 2) * 1024 + lane * 8;
                short8 bh0 = *(const short8*)(fb0);
                short8 bl0 = *(const short8*)(fb0 + 512);
                short8 bh1 = *(const short8*)(fb0 + 1024);
                short8 bl1 = *(const short8*)(fb0 + 1536);
                MFMA(ah[0], bh0, accB[0][0]);
                MFMA(ah[0], bl0, accB[0][0]);
                MFMA(al[0], bh0, accB[0][0]);
                MFMA(ah[0], bh1, accB[0][1]);
                MFMA(ah[0], bl1, accB[0][1]);
                MFMA(al[0], bh1, accB[0][1]);
                MFMA(ah[1], bh0, accB[1][0]);
                MFMA(ah[1], bl0, accB[1][0]);
                MFMA(al[1], bh0, accB[1][0]);
                MFMA(ah[1], bh1, accB[1][1]);
                MFMA(ah[1], bl1, accB[1][1]);
                MFMA(al[1], bh1, accB[1][1]);
            }
        }
    }

    // ================= cross-kq reduce + store =================
    __syncthreads();                    // all slab reads done; pool -> redbuf
    float* red = (float*)pool;          // [4 kq][32 p][128 d] f32 = 64 KB
    #pragma unroll
    for (int mt = 0; mt < 2; ++mt) {
        #pragma unroll
        for (int dti = 0; dti < 2; ++dti) {
            #pragma unroll
            for (int q = 0; q < 4; ++q) {
                int row = mt * 16 + g * 4 + q;
                int col = (dh * 2 + dti) * 16 + kk;
                red[(kq * 32 + row) * 128 + col] = accB[mt][dti][q];
            }
        }
    }
    __syncthreads();
    {
        int op = t >> 5, od = t & 31;
        const float4* r4 = (const float4*)red;
        float4 s0 = r4[(0 * 32 + op) * 32 + od];
        float4 s1 = r4[(1 * 32 + op) * 32 + od];
        float4 s2 = r4[(2 * 32 + op) * 32 + od];
        float4 s3 = r4[(3 * 32 + op) * 32 + od];
        float4 rv;
        rv.x = s0.x + s1.x + s2.x + s3.x;
        rv.y = s0.y + s1.y + s2.y + s3.y;
        rv.z = s0.z + s1.z + s2.z + s3.z;
        rv.w = s0.w + s1.w + s2.w + s3.w;
        if (m0 + op < M)
            ((float4*)out)[(m0 + op) * (CO / 4) + od] = rv;
    }
}

extern "C" void kernel_launch(void* const* d_in, const int* in_sizes, int n_in,
                              void* d_out, int out_size, void* d_ws, size_t ws_size,
                              hipStream_t stream)
{
    const float* q_pts   = (const float*)d_in[0];
    const float* s_pts   = (const float*)d_in[1];
    const float* s_feats = (const float*)d_in[2];
    const int*   nb      = (const int*)d_in[3];
    const float* weights = (const float*)d_in[4];
    const float* kpts    = (const float*)d_in[5];
    float*       out     = (float*)d_out;
    unsigned short* wpak = (unsigned short*)d_ws;            // 983040 B
    unsigned*       fpak = (unsigned*)((char*)d_ws + WOFF);  // N*128*4 B

    int M = in_sizes[0] / 3;
    int N = in_sizes[2] / CI;
    int grid = (M + MB - 1) / MB;

    hipLaunchKernelGGL(kpconv_prep_w, dim3(120), dim3(256), 0, stream, weights, wpak);

    size_t need = WOFF + (size_t)N * CI * 4;
    if (ws_size >= need) {
        int total4 = N * CI / 4;
        hipLaunchKernelGGL(kpconv_prep_f, dim3((total4 + 255) / 256), dim3(256),
                           0, stream, s_feats, fpak, total4);
        hipLaunchKernelGGL((kpconv_main<true>), dim3(grid), dim3(NT), 0, stream,
                           q_pts, s_pts, s_feats, nb, kpts, wpak, fpak, out, M);
    } else {
        hipLaunchKernelGGL((kpconv_main<false>), dim3(grid), dim3(NT), 0, stream,
                           q_pts, s_pts, s_feats, nb, kpts, wpak, fpak, out, M);
    }
}

// Round 6
// 320.050 us; speedup vs baseline: 1.0964x; 1.0964x over previous
//
#include <hip/hip_runtime.h>
#include <hip/hip_bf16.h>
#include <cmath>

// KPConv round 5b (compile-fixed R5): R3 structure (both einsums on bf16 MFMA,
// 3-term hi/lo), with
//  - direct f32 s_feats gathers (no fpak cache pollution — R4 lesson)
//  - compiler bf16 conversions (v_cvt_pk fusion) for feats/influence/slab writes
//  - per-j base pointers (offset-immediate gathers) + ping-pong gather buffer
//  - phase-B W-fragment prefetch across the slabs-ready barrier

constexpr int HN = 32;
constexpr int KP = 15;
constexpr int CI = 128;
constexpr int CO = 128;
constexpr int MB = 32;    // points per block
constexpr int NT = 1024;  // 16 waves
constexpr float INV_SIGMA = 0.5f;

using short8 = __attribute__((ext_vector_type(8))) short;
using f32x4  = __attribute__((ext_vector_type(4))) float;
using uint4v = __attribute__((ext_vector_type(4))) unsigned int;

static __device__ __forceinline__ unsigned short f2bf(float x) {
    unsigned u = __float_as_uint(x);
    u += 0x7fff + ((u >> 16) & 1);          // RNE (prep kernel only)
    return (unsigned short)(u >> 16);
}
static __device__ __forceinline__ float bf2f(unsigned short h) {
    return __uint_as_float(((unsigned)h) << 16);
}

// hi/lo split of a float pair via compiler bf16 converts (fuses to v_cvt_pk).
// h = bf16(a) | bf16(b)<<16 ; l = residuals likewise. Self-correcting: any
// hi rounding works since lo = rn(v - hi).
struct HL2 { unsigned h, l; };
static __device__ __forceinline__ HL2 split2(float a, float b) {
    __hip_bfloat162 hh = __float22bfloat162_rn(make_float2(a, b));
    float2 hf = __bfloat1622float2(hh);
    __hip_bfloat162 ll = __float22bfloat162_rn(make_float2(a - hf.x, b - hf.y));
    HL2 r;
    __builtin_memcpy(&r.h, &hh, 4);
    __builtin_memcpy(&r.l, &ll, 4);
    return r;
}

// ---- prep: W[15][128][128] f32 -> bf16 hi/lo MFMA-B fragments (R2/R3-verified) ----
// fb = (k*4 + s)*8 + dt; ushort layout fb*1024 + plane*512 + lane*8 + j.
// lane l elem j = W[k][c = s*32 + (l>>4)*8 + j][d = dt*16 + (l&15)]
__global__ void kpconv_prep_w(const float* __restrict__ w,
                              unsigned short* __restrict__ ws16) {
    int t = blockIdx.x * blockDim.x + threadIdx.x;
    int fb = t >> 6, lane = t & 63;
    if (fb >= 480) return;
    int k = fb >> 5, s = (fb >> 3) & 3, dt = fb & 7;
    int g = lane >> 4, n = lane & 15;
    unsigned short* base = ws16 + fb * 1024 + lane * 8;
    #pragma unroll
    for (int j = 0; j < 8; ++j) {
        int c = s * 32 + g * 8 + j;
        int d = dt * 16 + n;
        float v = w[(k * CI + c) * CO + d];
        unsigned short hi = f2bf(v);
        unsigned short lo = f2bf(v - bf2f(hi));
        base[j]       = (short)hi;
        base[512 + j] = (short)lo;
    }
}

#define MFMA(a, b, c) c = __builtin_amdgcn_mfma_f32_16x16x32_bf16(a, b, c, 0, 0, 0)

__global__ __launch_bounds__(NT)
void kpconv_main(const float* __restrict__ q_pts,
                 const float* __restrict__ s_pts,
                 const float* __restrict__ s_feats,
                 const int*   __restrict__ nb,
                 const float* __restrict__ kpts,
                 const unsigned short* __restrict__ wfr,
                 float* __restrict__ out, int M)
{
    __shared__ __align__(16) char pool[65536];

    const int t    = threadIdx.x;
    const int lane = t & 63;
    const int wid  = t >> 6;        // 0..15
    const int g    = lane >> 4;     // 0..3
    const int kk   = lane & 15;
    const int m0   = blockIdx.x * MB;

    const float kx = kpts[kk * 3 + 0];
    const float ky = kpts[kk * 3 + 1];
    const float kz = kpts[kk * 3 + 2];

    f32x4 accA[2][8] = {};   // wf: lane holds rows k=4g+r, col c=ct*16+kk

    // ================= Phase A =================
    #pragma unroll
    for (int pi = 0; pi < 2; ++pi) {
        const int  gp    = m0 + wid * 2 + pi;
        const bool valid = (gp < M);
        const int  rr    = valid ? gp : 0;
        const float qx = q_pts[rr * 3 + 0];
        const float qy = q_pts[rr * 3 + 1];
        const float qz = q_pts[rr * 3 + 2];

        int4 ia = *(const int4*)(nb + rr * HN + g * 8);
        int4 ib = *(const int4*)(nb + rr * HN + g * 8 + 4);
        int idx[8] = { ia.x, ia.y, ia.z, ia.w, ib.x, ib.y, ib.z, ib.w };

        // per-j feat base pointers: loads become bp[j] + const offset
        const float* bp[8];
        #pragma unroll
        for (int j = 0; j < 8; ++j) bp[j] = s_feats + idx[j] * CI + kk;

        // hoisted s_pts coordinate gathers (24 loads in flight together)
        float sx[8], sy[8], sz[8];
        #pragma unroll
        for (int j = 0; j < 8; ++j) {
            const float* sp = s_pts + idx[j] * 3;
            sx[j] = sp[0]; sy[j] = sp[1]; sz[j] = sp[2];
        }

        // influence values, then pack via cvt_pk pairs
        float vj[8];
        #pragma unroll
        for (int j = 0; j < 8; ++j) {
            float rx = sx[j] - qx, ry = sy[j] - qy, rz = sz[j] - qz;
            float dx = rx - kx, dy = ry - ky, dz = rz - kz;
            float d2 = dx * dx + dy * dy + dz * dz;
            float v  = fmaxf(1.0f - sqrtf(d2) * INV_SIGMA, 0.0f);
            vj[j] = (kk == 15 || !valid) ? 0.0f : v;
        }
        uint4v ihv, ilv;
        #pragma unroll
        for (int d = 0; d < 4; ++d) {
            HL2 r = split2(vj[2 * d], vj[2 * d + 1]);
            ihv[d] = r.h; ilv[d] = r.l;
        }
        short8 Ih = __builtin_bit_cast(short8, ihv);
        short8 Il = __builtin_bit_cast(short8, ilv);

        // ping-pong feat gather: >=8 loads always in flight
        float fb2[2][8];
        #pragma unroll
        for (int j = 0; j < 8; ++j) fb2[0][j] = bp[j][0];
        #pragma unroll
        for (int ct = 0; ct < 8; ++ct) {
            if (ct < 7) {
                #pragma unroll
                for (int j = 0; j < 8; ++j) fb2[(ct + 1) & 1][j] = bp[j][(ct + 1) * 16];
            }
            const float* f = fb2[ct & 1];
            uint4v hv, lv;
            #pragma unroll
            for (int d = 0; d < 4; ++d) {
                HL2 r = split2(f[2 * d], f[2 * d + 1]);
                hv[d] = r.h; lv[d] = r.l;
            }
            short8 Fh = __builtin_bit_cast(short8, hv);
            short8 Fl = __builtin_bit_cast(short8, lv);
            MFMA(Ih, Fh, accA[pi][ct]);
            MFMA(Ih, Fl, accA[pi][ct]);
            MFMA(Il, Fh, accA[pi][ct]);
        }
    }

    // ================= Phase B (R3-verified slab GEMM + W prefetch) =================
    const int kq = wid >> 2;    // k-quarter (slab id)
    const int dh = wid & 3;     // d-tiles {2dh, 2dh+1}
    f32x4 accB[2][2] = {};

    #pragma unroll
    for (int tr = 0; tr < 4; ++tr) {
        if (tr) __syncthreads();        // previous round's slab reads done
        // --- write slabs: k = 4g + tr (slab g), value = acc component tr ---
        #pragma unroll
        for (int pi = 0; pi < 2; ++pi) {
            const int prow = wid * 2 + pi;
            char* rowbase = pool + g * 16384 + prow * 256;
            const int rowx = (prow & 7) << 4;
            #pragma unroll
            for (int cp = 0; cp < 4; ++cp) {
                HL2 r = split2(accA[pi][2 * cp][tr], accA[pi][2 * cp + 1][tr]);
                int c2a  = ((2 * cp) * 16 + kk) * 2;
                int c2b  = ((2 * cp + 1) * 16 + kk) * 2;
                int offa = (c2a ^ (g << 5)) ^ rowx;
                int offb = (c2b ^ (g << 5)) ^ rowx;
                *(unsigned short*)(rowbase + offa)        = (unsigned short)(r.h & 0xffffu);
                *(unsigned short*)(rowbase + offb)        = (unsigned short)(r.h >> 16);
                *(unsigned short*)(rowbase + 8192 + offa) = (unsigned short)(r.l & 0xffffu);
                *(unsigned short*)(rowbase + 8192 + offb) = (unsigned short)(r.l >> 16);
            }
        }
        // --- prefetch W-frags for (k, sc=0) BEFORE the barrier (independent of slabs) ---
        const int  k  = 4 * kq + tr;
        const bool kv = (k < KP);
        short8 cbh0, cbl0, cbh1, cbl1;
        if (kv) {
            const unsigned short* fb0 = wfr + ((k * 4 + 0) * 8 + dh * 2) * 1024 + lane * 8;
            cbh0 = *(const short8*)(fb0);
            cbl0 = *(const short8*)(fb0 + 512);
            cbh1 = *(const short8*)(fb0 + 1024);
            cbl1 = *(const short8*)(fb0 + 1536);
        }
        __syncthreads();                // slabs ready
        if (kv) {
            #pragma unroll
            for (int sc = 0; sc < 4; ++sc) {
                // issue next sc's W loads before this sc's LDS reads
                short8 nh0, nl0, nh1, nl1;
                if (sc < 3) {
                    const unsigned short* fbn =
                        wfr + ((k * 4 + sc + 1) * 8 + dh * 2) * 1024 + lane * 8;
                    nh0 = *(const short8*)(fbn);
                    nl0 = *(const short8*)(fbn + 512);
                    nh1 = *(const short8*)(fbn + 1024);
                    nl1 = *(const short8*)(fbn + 1536);
                }
                short8 ah[2], al[2];
                #pragma unroll
                for (int mt = 0; mt < 2; ++mt) {
                    int row = mt * 16 + kk;
                    int c2  = sc * 64 + g * 16;
                    int off = (c2 ^ (kq << 5)) ^ ((row & 7) << 4);
                    const char* base = pool + kq * 16384 + row * 256 + off;
                    ah[mt] = *(const short8*)(base);
                    al[mt] = *(const short8*)(base + 8192);
                }
                MFMA(ah[0], cbh0, accB[0][0]);
                MFMA(ah[0], cbl0, accB[0][0]);
                MFMA(al[0], cbh0, accB[0][0]);
                MFMA(ah[0], cbh1, accB[0][1]);
                MFMA(ah[0], cbl1, accB[0][1]);
                MFMA(al[0], cbh1, accB[0][1]);
                MFMA(ah[1], cbh0, accB[1][0]);
                MFMA(ah[1], cbl0, accB[1][0]);
                MFMA(al[1], cbh0, accB[1][0]);
                MFMA(ah[1], cbh1, accB[1][1]);
                MFMA(ah[1], cbl1, accB[1][1]);
                MFMA(al[1], cbh1, accB[1][1]);
                if (sc < 3) { cbh0 = nh0; cbl0 = nl0; cbh1 = nh1; cbl1 = nl1; }
            }
        }
    }

    // ================= cross-kq reduce + store =================
    __syncthreads();                    // all slab reads done; pool -> redbuf
    float* red = (float*)pool;          // [4 kq][32 p][128 d] f32 = 64 KB
    #pragma unroll
    for (int mt = 0; mt < 2; ++mt) {
        #pragma unroll
        for (int dti = 0; dti < 2; ++dti) {
            #pragma unroll
            for (int q = 0; q < 4; ++q) {
                int row = mt * 16 + g * 4 + q;
                int col = (dh * 2 + dti) * 16 + kk;
                red[(kq * 32 + row) * 128 + col] = accB[mt][dti][q];
            }
        }
    }
    __syncthreads();
    {
        int op = t >> 5, od = t & 31;
        const float4* r4 = (const float4*)red;
        float4 s0 = r4[(0 * 32 + op) * 32 + od];
        float4 s1 = r4[(1 * 32 + op) * 32 + od];
        float4 s2 = r4[(2 * 32 + op) * 32 + od];
        float4 s3 = r4[(3 * 32 + op) * 32 + od];
        float4 rv;
        rv.x = s0.x + s1.x + s2.x + s3.x;
        rv.y = s0.y + s1.y + s2.y + s3.y;
        rv.z = s0.z + s1.z + s2.z + s3.z;
        rv.w = s0.w + s1.w + s2.w + s3.w;
        if (m0 + op < M)
            ((float4*)out)[(m0 + op) * (CO / 4) + od] = rv;
    }
}

extern "C" void kernel_launch(void* const* d_in, const int* in_sizes, int n_in,
                              void* d_out, int out_size, void* d_ws, size_t ws_size,
                              hipStream_t stream)
{
    const float* q_pts   = (const float*)d_in[0];
    const float* s_pts   = (const float*)d_in[1];
    const float* s_feats = (const float*)d_in[2];
    const int*   nb      = (const int*)d_in[3];
    const float* weights = (const float*)d_in[4];
    const float* kpts    = (const float*)d_in[5];
    float*       out     = (float*)d_out;
    unsigned short* wpak = (unsigned short*)d_ws;   // 983040 B of workspace

    int M = in_sizes[0] / 3;
    int grid = (M + MB - 1) / MB;

    hipLaunchKernelGGL(kpconv_prep_w, dim3(120), dim3(256), 0, stream, weights, wpak);
    hipLaunchKernelGGL(kpconv_main, dim3(grid), dim3(NT), 0, stream,
                       q_pts, s_pts, s_feats, nb, kpts, wpak, out, M);
}